// Round 3
// baseline (352.278 us; speedup 1.0000x reference)
//
#include <hip/hip_runtime.h>

#define LOG2E 1.44269504088896340736f

__device__ __forceinline__ float fast_exp2(float x) {
#if __has_builtin(__builtin_amdgcn_exp2f)
    return __builtin_amdgcn_exp2f(x);
#else
    return exp2f(x);
#endif
}

constexpr int BATCH = 32;
constexpr int HGT = 256;
constexpr int WID = 256;
constexpr int CH = 3;
constexpr int KPAL = 32;
constexpr int PIX_PER_BATCH = HGT * WID;            // 65536
constexpr int THREADS = 256;
constexpr int PIX_PER_THREAD = 4;
constexpr int BLOCKS_PER_BATCH = PIX_PER_BATCH / (THREADS * PIX_PER_THREAD);  // 64

// One thread handles 4 consecutive pixels (12 contiguous floats -> 3x float4).
// Softmax over K with the |x|^2 term dropped (shift-invariant), exp2-native,
// and the combine accumulated against the pre-scaled palette coefficients.
__global__ __launch_bounds__(THREADS, 8)
void palette_quant_kernel(const float* __restrict__ images,
                          const float* __restrict__ palettes,
                          const float* __restrict__ temp,
                          float* __restrict__ out)
{
    __shared__ float4 ab[KPAL];   // (a0, a1, a2, b) per palette entry
    __shared__ float s_fs;        // final-scale constant T/(2*log2e)

    const int batch = blockIdx.x >> 6;  // / BLOCKS_PER_BATCH

    if (threadIdx.x < KPAL) {
        const float T = *temp;
        const float cinv = LOG2E / T;
        const float* p = palettes + (batch * KPAL + threadIdx.x) * CH;
        const float p0 = p[0], p1 = p[1], p2 = p[2];
        const float b = -(p0 * p0 + p1 * p1 + p2 * p2) * cinv;
        const float c2 = 2.0f * cinv;
        ab[threadIdx.x] = make_float4(p0 * c2, p1 * c2, p2 * c2, b);
        if (threadIdx.x == 0) s_fs = T * (0.5f / LOG2E);
    }
    __syncthreads();

    const int tid = ((blockIdx.x & 63) << 8) | threadIdx.x;  // 0..16383 within batch
    const long long base = (long long)batch * (PIX_PER_BATCH * CH)
                         + (long long)tid * (PIX_PER_THREAD * CH);

    const float4* ip = reinterpret_cast<const float4*>(images + base);
    const float4 v0 = ip[0];
    const float4 v1 = ip[1];
    const float4 v2 = ip[2];

    // De-interleave 4 pixels' RGB
    const float x0[4] = {v0.x, v0.w, v1.z, v2.y};
    const float x1[4] = {v0.y, v1.x, v1.w, v2.z};
    const float x2[4] = {v0.z, v1.y, v2.x, v2.w};

    float sum[4] = {0.f, 0.f, 0.f, 0.f};
    float o0[4]  = {0.f, 0.f, 0.f, 0.f};
    float o1[4]  = {0.f, 0.f, 0.f, 0.f};
    float o2[4]  = {0.f, 0.f, 0.f, 0.f};

#pragma unroll
    for (int k = 0; k < KPAL; ++k) {
        const float4 a = ab[k];   // uniform address -> LDS broadcast, conflict-free
#pragma unroll
        for (int j = 0; j < PIX_PER_THREAD; ++j) {
            float s = fmaf(x0[j], a.x, a.w);
            s = fmaf(x1[j], a.y, s);
            s = fmaf(x2[j], a.z, s);
            const float w = fast_exp2(s);
            sum[j] += w;
            o0[j] = fmaf(w, a.x, o0[j]);
            o1[j] = fmaf(w, a.y, o1[j]);
            o2[j] = fmaf(w, a.z, o2[j]);
        }
    }

    const float fs = s_fs;
    float r[4];
#pragma unroll
    for (int j = 0; j < PIX_PER_THREAD; ++j)
        r[j] = fs * __builtin_amdgcn_rcpf(sum[j]);

    const float4 w0 = make_float4(o0[0] * r[0], o1[0] * r[0], o2[0] * r[0], o0[1] * r[1]);
    const float4 w1 = make_float4(o1[1] * r[1], o2[1] * r[1], o0[2] * r[2], o1[2] * r[2]);
    const float4 w2 = make_float4(o2[2] * r[2], o0[3] * r[3], o1[3] * r[3], o2[3] * r[3]);

    float4* op = reinterpret_cast<float4*>(out + base);
    op[0] = w0;
    op[1] = w1;
    op[2] = w2;
}

extern "C" void kernel_launch(void* const* d_in, const int* in_sizes, int n_in,
                              void* d_out, int out_size, void* d_ws, size_t ws_size,
                              hipStream_t stream) {
    const float* images   = (const float*)d_in[0];
    const float* palettes = (const float*)d_in[1];
    const float* temp     = (const float*)d_in[2];
    float* out            = (float*)d_out;

    palette_quant_kernel<<<dim3(BATCH * BLOCKS_PER_BATCH), dim3(THREADS), 0, stream>>>(
        images, palettes, temp, out);
}

// Round 6
// 87.673 us; speedup vs baseline: 4.0181x; 4.0181x over previous
//
#include <hip/hip_runtime.h>

#define LOG2E 1.44269504088896340736f

__device__ __forceinline__ float fast_exp2(float x) {
#if __has_builtin(__builtin_amdgcn_exp2f)
    return __builtin_amdgcn_exp2f(x);
#else
    return exp2f(x);
#endif
}

constexpr int BATCH = 32;
constexpr int CH = 3;
constexpr int KPAL = 32;
constexpr int PIX_PER_BATCH = 256 * 256;                    // 65536
constexpr int THREADS = 256;
constexpr int BLOCKS_PER_BATCH = PIX_PER_BATCH / THREADS;   // 256
constexpr int NBLOCKS = BATCH * BLOCKS_PER_BATCH;           // 8192

// 12-byte pixel; alignment 4 is all global_load_dwordx3 needs.
struct F3 { float x, y, z; };

// One thread = one pixel. NO indexed arrays anywhere -> nothing can be
// demoted to scratch (Round-2 kernel lost 24x to spill traffic).
// Softmax over K with |x|^2 dropped (shift-invariant), exp2-native, and the
// combine accumulated against pre-scaled palette coeffs (fixed up by one
// final scale r = T/(2*log2e) / sum).
__global__ __launch_bounds__(THREADS, 8)
void palette_quant_kernel(const float* __restrict__ images,
                          const float* __restrict__ palettes,
                          const float* __restrict__ temp,
                          float* __restrict__ out)
{
    __shared__ float4 ab[KPAL];   // (a0, a1, a2, b) per palette entry
    __shared__ float s_fs;        // final-scale constant T/(2*log2e)

    const int batch = blockIdx.x >> 8;   // / BLOCKS_PER_BATCH

    if (threadIdx.x < KPAL) {
        const float T = *temp;
        const float cinv = LOG2E / T;
        const float* p = palettes + (batch * KPAL + threadIdx.x) * CH;
        const float p0 = p[0], p1 = p[1], p2 = p[2];
        const float b = -(p0 * p0 + p1 * p1 + p2 * p2) * cinv;
        const float c2 = 2.0f * cinv;
        ab[threadIdx.x] = make_float4(p0 * c2, p1 * c2, p2 * c2, b);
        if (threadIdx.x == 0) s_fs = T * (0.5f / LOG2E);
    }
    __syncthreads();

    const long long pix  = (long long)blockIdx.x * THREADS + threadIdx.x;
    const long long base = pix * CH;

    const F3 v = *reinterpret_cast<const F3*>(images + base);
    const float x0 = v.x, x1 = v.y, x2 = v.z;

    float sum = 0.f, o0 = 0.f, o1 = 0.f, o2 = 0.f;

#pragma unroll
    for (int k = 0; k < KPAL; ++k) {
        const float4 a = ab[k];   // uniform address -> LDS broadcast, conflict-free
        float s = fmaf(x0, a.x, a.w);
        s = fmaf(x1, a.y, s);
        s = fmaf(x2, a.z, s);
        const float w = fast_exp2(s);
        sum += w;
        o0 = fmaf(w, a.x, o0);
        o1 = fmaf(w, a.y, o1);
        o2 = fmaf(w, a.z, o2);
    }

    const float r = s_fs * __builtin_amdgcn_rcpf(sum);
    F3 o;
    o.x = o0 * r;
    o.y = o1 * r;
    o.z = o2 * r;
    *reinterpret_cast<F3*>(out + base) = o;
}

extern "C" void kernel_launch(void* const* d_in, const int* in_sizes, int n_in,
                              void* d_out, int out_size, void* d_ws, size_t ws_size,
                              hipStream_t stream) {
    const float* images   = (const float*)d_in[0];
    const float* palettes = (const float*)d_in[1];
    const float* temp     = (const float*)d_in[2];
    float* out            = (float*)d_out;

    palette_quant_kernel<<<dim3(NBLOCKS), dim3(THREADS), 0, stream>>>(
        images, palettes, temp, out);
}